// Round 1
// baseline (899.338 us; speedup 1.0000x reference)
//
#include <hip/hip_runtime.h>
#include <stdint.h>

#define SCORE_THRESH 0.05f
#define IOU_THRESH 0.5f
#define TOP_K 1000
#define MAX_DET 100

typedef unsigned int u32;
typedef unsigned long long u64;

// ---- ws layout (bytes) ----
#define OFF_HIST     0          // u32[65536]  = 262144
#define OFF_STATE    262144     // u32[6]: [0]=k_rem [1..4]=digits [5]=cand_cnt
#define OFF_KEEP     262400     // u64[16]
#define OFF_CANDIDX  262528     // u32[1024]
#define OFF_SIDX     266624     // u32[1024]
#define OFF_SSCORE   270720     // float[1024]
#define OFF_CBOX     274816     // float[1000*4]
#define OFF_M        291200     // u64[1000*16] = 128000
#define OFF_SCORES   419200     // float[A]

__device__ __forceinline__ u32 order_f32(float f) {
    u32 b = __float_as_uint(f);
    return (b & 0x80000000u) ? ~b : (b | 0x80000000u);
}

// K1: per-anchor score (max over C classes), thresholded s0, + pass-0 histogram
// of key32>>16 with wave-aggregated atomics (hot-bin contention mitigation).
__global__ void k_scores_hist(const float* __restrict__ cls, int A, int C,
                              float* __restrict__ scores, u32* __restrict__ hist) {
    int a = blockIdx.x * blockDim.x + threadIdx.x;
    bool have = (a < A);
    float s0 = -1.0f;
    if (have) {
        const float* p = cls + (size_t)a * C;
        float m = -1e30f;
        int c = 0;
        for (; c + 4 <= C; c += 4) {
            float4 v = *(const float4*)(p + c);
            m = fmaxf(m, fmaxf(fmaxf(v.x, v.y), fmaxf(v.z, v.w)));
        }
        for (; c < C; c++) m = fmaxf(m, p[c]);
        s0 = (m > SCORE_THRESH) ? m : -1.0f;
        scores[a] = s0;
    }
    u32 digit = have ? (order_f32(s0) >> 16) : 0xFFFFFFFFu;
    int lane = threadIdx.x & 63;
    u64 remaining = __ballot(have ? 1 : 0);
    while (remaining) {
        int leader = __ffsll(remaining) - 1;
        u32 dl = (u32)__shfl((int)digit, leader, 64);
        u64 match = __ballot((have && digit == dl) ? 1 : 0);
        if (lane == leader) atomicAdd(&hist[dl], (u32)__popcll(match));
        remaining &= ~match;
    }
}

// Radix-select scan: find digit where cumulative-from-top crosses k_rem.
// Also zeroes the histogram for reuse by the next pass.
__global__ void __launch_bounds__(1024) k_scan(u32* __restrict__ hist,
                                               u32* __restrict__ state, int pass) {
    __shared__ u32 wtot[16];
    int t = threadIdx.x;
    int lane = t & 63, wv = t >> 6;
    u32 k = (pass == 0) ? (u32)TOP_K : state[0];   // read BEFORE any write
    int base = t * 64;
    u32 s = 0;
    for (int i = 0; i < 64; i++) s += hist[base + i];
    // suffix-inclusive scan within wave (sum over lanes >= mine)
    u32 x = s;
    for (int off = 1; off < 64; off <<= 1) {
        u32 v = (u32)__shfl_down((int)x, off, 64);
        if (lane + off < 64) x += v;
    }
    if (lane == 0) wtot[wv] = x;   // wave total
    __syncthreads();               // also orders state[0] reads before write below
    u32 above = x - s;             // lanes above me in my wave
    for (int w = wv + 1; w < 16; w++) above += wtot[w];
    if (above < k && above + s >= k) {
        u32 cum = above;
        for (int b = 63; b >= 0; b--) {
            u32 c = hist[base + b];
            cum += c;
            if (cum >= k) {
                state[1 + pass] = (u32)(base + b);
                state[0] = k - (cum - c);
                break;
            }
        }
    }
    for (int i = 0; i < 64; i++) hist[base + i] = 0;
}

__global__ void k_hist2(const float* __restrict__ scores, int A,
                        u32* __restrict__ hist, const u32* __restrict__ state) {
    int a = blockIdx.x * blockDim.x + threadIdx.x;
    if (a >= A) return;
    u32 key = order_f32(scores[a]);
    if ((key >> 16) == state[1]) atomicAdd(&hist[key & 0xFFFFu], 1u);
}

__global__ void k_hist3(const float* __restrict__ scores, int A,
                        u32* __restrict__ hist, const u32* __restrict__ state) {
    int a = blockIdx.x * blockDim.x + threadIdx.x;
    if (a >= A) return;
    u32 key = order_f32(scores[a]);
    u32 p32 = (state[1] << 16) | state[2];
    if (key == p32) {
        u32 ik = 0xFFFFFFFFu - (u32)a;
        atomicAdd(&hist[ik >> 16], 1u);
    }
}

__global__ void k_hist4(const float* __restrict__ scores, int A,
                        u32* __restrict__ hist, const u32* __restrict__ state) {
    int a = blockIdx.x * blockDim.x + threadIdx.x;
    if (a >= A) return;
    u32 key = order_f32(scores[a]);
    u32 p32 = (state[1] << 16) | state[2];
    if (key == p32) {
        u32 ik = 0xFFFFFFFFu - (u32)a;
        if ((ik >> 16) == state[3]) atomicAdd(&hist[ik & 0xFFFFu], 1u);
    }
}

// Compact: exactly TOP_K elements have key64 >= T (keys unique per anchor).
__global__ void k_compact(const float* __restrict__ scores, int A,
                          u32* __restrict__ state, u32* __restrict__ cand_idx) {
    int a = blockIdx.x * blockDim.x + threadIdx.x;
    if (a >= A) return;
    u32 key = order_f32(scores[a]);
    u32 ik = 0xFFFFFFFFu - (u32)a;
    u64 k64 = ((u64)key << 32) | ik;
    u64 T = ((u64)((state[1] << 16) | state[2]) << 32) |
            (u64)((state[3] << 16) | state[4]);
    if (k64 >= T) {
        u32 p = atomicAdd(&state[5], 1u);
        if (p < TOP_K) cand_idx[p] = a;
    }
}

// Bitonic sort 1024 u64 keys descending (= lax.top_k order), then decode+clip
// boxes for the sorted 1000 candidates.
__global__ void __launch_bounds__(1024)
k_sort_decode(const float* __restrict__ scores, const u32* __restrict__ cand_idx,
              const float* __restrict__ anchors, const float* __restrict__ regs,
              const int* __restrict__ pH, const int* __restrict__ pW,
              u32* __restrict__ sidx, float* __restrict__ sscore,
              float* __restrict__ cbox) {
    __shared__ u64 keys[1024];
    int t = threadIdx.x;
    if (t < TOP_K) {
        u32 a = cand_idx[t];
        keys[t] = ((u64)order_f32(scores[a]) << 32) | (0xFFFFFFFFu - a);
    } else {
        keys[t] = 0ull;  // real keys are always > 0; pads sort last
    }
    __syncthreads();
    for (int k = 2; k <= 1024; k <<= 1) {
        for (int j = k >> 1; j > 0; j >>= 1) {
            int ixj = t ^ j;
            if (ixj > t) {
                u64 va = keys[t], vb = keys[ixj];
                bool desc = ((t & k) == 0);
                if (desc ? (va < vb) : (va > vb)) { keys[t] = vb; keys[ixj] = va; }
            }
            __syncthreads();
        }
    }
    if (t < TOP_K) {
        u64 key = keys[t];
        u32 a = 0xFFFFFFFFu - (u32)(key & 0xFFFFFFFFull);
        sidx[t] = a;
        u32 kk = (u32)(key >> 32);
        u32 bits = (kk & 0x80000000u) ? (kk & 0x7FFFFFFFu) : ~kk;
        sscore[t] = __uint_as_float(bits);
        // decode + clip (BBoxTransform, std [0.1,0.1,0.2,0.2])
        float4 an = *(const float4*)(anchors + (size_t)a * 4);
        float4 rg = *(const float4*)(regs + (size_t)a * 4);
        float aw = an.z - an.x, ah = an.w - an.y;
        float acx = an.x + 0.5f * aw, acy = an.y + 0.5f * ah;
        float pcx = acx + (rg.x * 0.1f) * aw;
        float pcy = acy + (rg.y * 0.1f) * ah;
        float pw = __expf(rg.z * 0.2f) * aw;  // replaced below if precision issue
        float ph = __expf(rg.w * 0.2f) * ah;
        // use precise expf to track jnp.exp closely
        pw = expf(rg.z * 0.2f) * aw;
        ph = expf(rg.w * 0.2f) * ah;
        float W = (float)(*pW), H = (float)(*pH);
        float x1 = fminf(fmaxf(pcx - 0.5f * pw, 0.0f), W);
        float y1 = fminf(fmaxf(pcy - 0.5f * ph, 0.0f), H);
        float x2 = fminf(fmaxf(pcx + 0.5f * pw, 0.0f), W);
        float y2 = fminf(fmaxf(pcy + 0.5f * ph, 0.0f), H);
        cbox[t * 4 + 0] = x1;
        cbox[t * 4 + 1] = y1;
        cbox[t * 4 + 2] = x2;
        cbox[t * 4 + 3] = y2;
    }
}

// Suppression bit-matrix: M[i][w] bit b = (j = w*64+b) suppressed by i.
__global__ void k_iou(const float* __restrict__ cbox, u64* __restrict__ M) {
    __shared__ float4 boxes[TOP_K];
    int t = threadIdx.x;
    for (int j = t; j < TOP_K; j += 256) boxes[j] = ((const float4*)cbox)[j];
    __syncthreads();
    int wv = t >> 6, lane = t & 63;
    int i = blockIdx.x * 4 + wv;
    if (i < TOP_K) {
        float4 bi = boxes[i];
        float ai = fmaxf(bi.z - bi.x, 0.0f) * fmaxf(bi.w - bi.y, 0.0f);
        for (int w = 0; w < 16; w++) {
            int j = w * 64 + lane;
            bool sup = false;
            if (j < TOP_K && j > i) {
                float4 bj = boxes[j];
                float aj = fmaxf(bj.z - bj.x, 0.0f) * fmaxf(bj.w - bj.y, 0.0f);
                float xx1 = fmaxf(bi.x, bj.x), yy1 = fmaxf(bi.y, bj.y);
                float xx2 = fminf(bi.z, bj.z), yy2 = fminf(bi.w, bj.w);
                float inter = fmaxf(xx2 - xx1, 0.0f) * fmaxf(yy2 - yy1, 0.0f);
                float iou = inter / (ai + aj - inter + 1e-8f);
                sup = iou > IOU_THRESH;
            }
            u64 mask = __ballot(sup ? 1 : 0);
            if (lane == 0) M[(size_t)i * 16 + w] = mask;
        }
    }
}

// Sequential greedy reduction over the bit-matrix. One wave: lane w owns word w.
__global__ void k_nms_reduce(const float* __restrict__ sscore,
                             const u64* __restrict__ M, u64* __restrict__ keep_out) {
    int lane = threadIdx.x;  // 64 threads
    u64 keep = 0ull;
    if (lane < 16) {
        for (int b = 0; b < 64; b++) {
            int j = lane * 64 + b;
            if (j < TOP_K && sscore[j] > SCORE_THRESH) keep |= (1ull << b);
        }
    }
    for (int i = 0; i < TOP_K; i++) {
        u64 m = (lane < 16) ? M[(size_t)i * 16 + lane] : 0ull;
        u64 kw = __shfl(keep, i >> 6, 64);
        if ((kw >> (i & 63)) & 1ull) keep &= ~m;
    }
    if (lane < 16) keep_out[lane] = keep;
}

// Final gather: first MAX_DET kept candidates (ascending i = score-desc order),
// recompute class max/argmax, write [scores(100) | class(100) | boxes(100*4)].
__global__ void k_finalize(const float* __restrict__ cls, int C,
                           const u32* __restrict__ sidx,
                           const float* __restrict__ cbox,
                           const u64* __restrict__ keep,
                           float* __restrict__ out) {
    __shared__ int det[MAX_DET];
    if (threadIdx.x == 0) {
        int cnt = 0;
        for (int w = 0; w < 16 && cnt < MAX_DET; w++) {
            u64 kw = keep[w];
            while (kw && cnt < MAX_DET) {
                int b = __ffsll(kw) - 1;
                det[cnt++] = w * 64 + b;
                kw &= kw - 1;
            }
        }
        for (; cnt < MAX_DET; cnt++) det[cnt] = -1;
    }
    __syncthreads();
    int t = threadIdx.x;
    if (t < MAX_DET) {
        int i = det[t];
        if (i >= 0) {
            u32 a = sidx[i];
            const float* p = cls + (size_t)a * C;
            float best = p[0];
            int bc = 0;
            for (int c = 1; c < C; c++) {
                float v = p[c];
                if (v > best) { best = v; bc = c; }  // first-occurrence argmax
            }
            out[t] = best;
            out[MAX_DET + t] = (float)bc;
            out[2 * MAX_DET + t * 4 + 0] = cbox[i * 4 + 0];
            out[2 * MAX_DET + t * 4 + 1] = cbox[i * 4 + 1];
            out[2 * MAX_DET + t * 4 + 2] = cbox[i * 4 + 2];
            out[2 * MAX_DET + t * 4 + 3] = cbox[i * 4 + 3];
        } else {
            out[t] = 0.0f;
            out[MAX_DET + t] = -1.0f;
            out[2 * MAX_DET + t * 4 + 0] = 0.0f;
            out[2 * MAX_DET + t * 4 + 1] = 0.0f;
            out[2 * MAX_DET + t * 4 + 2] = 0.0f;
            out[2 * MAX_DET + t * 4 + 3] = 0.0f;
        }
    }
}

extern "C" void kernel_launch(void* const* d_in, const int* in_sizes, int n_in,
                              void* d_out, int out_size, void* d_ws, size_t ws_size,
                              hipStream_t stream) {
    const float* cls     = (const float*)d_in[0];
    const float* regs    = (const float*)d_in[1];
    const float* anchors = (const float*)d_in[2];
    const int*   pH      = (const int*)d_in[3];
    const int*   pW      = (const int*)d_in[4];
    int A = in_sizes[1] / 4;      // regressions [1,A,4]
    int C = in_sizes[0] / A;      // classifications [1,A,C]

    char* ws = (char*)d_ws;
    u32*   hist     = (u32*)(ws + OFF_HIST);
    u32*   state    = (u32*)(ws + OFF_STATE);
    u64*   keep     = (u64*)(ws + OFF_KEEP);
    u32*   cand_idx = (u32*)(ws + OFF_CANDIDX);
    u32*   sidx     = (u32*)(ws + OFF_SIDX);
    float* sscore   = (float*)(ws + OFF_SSCORE);
    float* cbox     = (float*)(ws + OFF_CBOX);
    u64*   M        = (u64*)(ws + OFF_M);
    float* scores   = (float*)(ws + OFF_SCORES);

    // zero hist + state (k_rem/digits/cand_cnt); ws is re-poisoned each call
    hipMemsetAsync(ws, 0, OFF_KEEP, stream);

    int nb = (A + 255) / 256;
    k_scores_hist<<<nb, 256, 0, stream>>>(cls, A, C, scores, hist);
    k_scan<<<1, 1024, 0, stream>>>(hist, state, 0);
    k_hist2<<<nb, 256, 0, stream>>>(scores, A, hist, state);
    k_scan<<<1, 1024, 0, stream>>>(hist, state, 1);
    k_hist3<<<nb, 256, 0, stream>>>(scores, A, hist, state);
    k_scan<<<1, 1024, 0, stream>>>(hist, state, 2);
    k_hist4<<<nb, 256, 0, stream>>>(scores, A, hist, state);
    k_scan<<<1, 1024, 0, stream>>>(hist, state, 3);
    k_compact<<<nb, 256, 0, stream>>>(scores, A, state, cand_idx);
    k_sort_decode<<<1, 1024, 0, stream>>>(scores, cand_idx, anchors, regs, pH, pW,
                                          sidx, sscore, cbox);
    k_iou<<<(TOP_K + 3) / 4, 256, 0, stream>>>(cbox, M);
    k_nms_reduce<<<1, 64, 0, stream>>>(sscore, M, keep);
    k_finalize<<<1, 128, 0, stream>>>(cls, C, sidx, cbox, keep, (float*)d_out);
}

// Round 2
// 312.303 us; speedup vs baseline: 2.8797x; 2.8797x over previous
//
#include <hip/hip_runtime.h>
#include <stdint.h>

#define SCORE_THRESH 0.05f
#define IOU_THRESH 0.5f
#define TOP_K 1000
#define MAX_DET 100

#define D0_BITS 13
#define D0_BINS 8192           // 2^13
#define NREP 16                // replicated pass-0 histograms
#define CAND_CAP 2048

typedef unsigned int u32;
typedef unsigned long long u64;

// ---- ws layout (bytes) ----
#define OFF_HIST0    0          // u32[NREP*8192] = 524288
#define OFF_HIST1    524288     // u32[65536]     = 262144 -> 786432
#define OFF_STATE    786432     // u32[8]: [0]=k_rem [1]=d0cut [2]=d1cut [5]=cand_cnt
#define OFF_CAND     786464     // u32[2048]  -> 794656
#define OFF_SIDX     794656     // u32[1000]  -> 798656
#define OFF_SSCORE   798656     // float[1000]-> 802656
#define OFF_CBOX     802656     // float[4000]-> 818656 (16B aligned)
#define OFF_M        818656     // u64[1000*16] = 128000 -> 946656
#define OFF_SCORES   946656     // float[A]

__device__ __forceinline__ u32 order_f32(float f) {
    u32 b = __float_as_uint(f);
    return (b & 0x80000000u) ? ~b : (b | 0x80000000u);
}

// ---------------------------------------------------------------------------
// K1: coalesced class-max (4 lanes per anchor, float4), thresholded score,
// LDS-privatized 13-bit pass-0 histogram, flushed to replicated global hist.
// Block=256 threads handles 6 stripes x 64 anchors = 384 anchors.
// ---------------------------------------------------------------------------
__global__ void __launch_bounds__(256) k1_scores(const float* __restrict__ cls, int A,
                                                 float* __restrict__ scores,
                                                 u32* __restrict__ hist0) {
    __shared__ u32 hl[D0_BINS / 2];   // u16-packed counts (per-block max 384 < 65536)
    int t = threadIdx.x;
    for (int i = t; i < D0_BINS / 2; i += 256) hl[i] = 0;
    __syncthreads();

    int sub = t & 3;          // which 20-float chunk of the anchor's 80 classes
    int la  = t >> 2;         // local anchor 0..63
    for (int s = 0; s < 6; s++) {
        int a = (blockIdx.x * 6 + s) * 64 + la;
        float m = -1e30f;
        if (a < A) {
            const float* p = cls + (size_t)a * 80 + sub * 4;
            #pragma unroll
            for (int k2 = 0; k2 < 5; k2++) {
                float4 v = *(const float4*)(p + k2 * 16);
                m = fmaxf(m, fmaxf(fmaxf(v.x, v.y), fmaxf(v.z, v.w)));
            }
        }
        m = fmaxf(m, __shfl_xor(m, 1, 64));
        m = fmaxf(m, __shfl_xor(m, 2, 64));
        if (sub == 0 && a < A) {
            float s0 = (m > SCORE_THRESH) ? m : -1.0f;
            scores[a] = s0;
            u32 d = order_f32(s0) >> (32 - D0_BITS);
            atomicAdd(&hl[d >> 1], (d & 1) ? 0x10000u : 1u);
        }
    }
    __syncthreads();
    // flush to replica (blockIdx & 15): worst-case same-address atomics = 32/replica
    u32* rep = hist0 + (size_t)(blockIdx.x & (NREP - 1)) * D0_BINS;
    for (int i = t; i < D0_BINS / 2; i += 256) {
        u32 v = hl[i];
        if (v & 0xFFFFu) atomicAdd(&rep[2 * i],     v & 0xFFFFu);
        if (v >> 16)     atomicAdd(&rep[2 * i + 1], v >> 16);
    }
}

// Generic-C fallback (correctness insurance if C != 80). Block=256, 512 anchors/block.
__global__ void __launch_bounds__(256) k1_generic(const float* __restrict__ cls, int A, int C,
                                                  float* __restrict__ scores,
                                                  u32* __restrict__ hist0) {
    __shared__ u32 hl[D0_BINS / 2];
    int t = threadIdx.x;
    for (int i = t; i < D0_BINS / 2; i += 256) hl[i] = 0;
    __syncthreads();
    for (int s = 0; s < 2; s++) {
        int a = blockIdx.x * 512 + s * 256 + t;
        if (a < A) {
            const float* p = cls + (size_t)a * C;
            float m = -1e30f;
            for (int c = 0; c < C; c++) m = fmaxf(m, p[c]);
            float s0 = (m > SCORE_THRESH) ? m : -1.0f;
            scores[a] = s0;
            u32 d = order_f32(s0) >> (32 - D0_BITS);
            atomicAdd(&hl[d >> 1], (d & 1) ? 0x10000u : 1u);
        }
    }
    __syncthreads();
    u32* rep = hist0 + (size_t)(blockIdx.x & (NREP - 1)) * D0_BINS;
    for (int i = t; i < D0_BINS / 2; i += 256) {
        u32 v = hl[i];
        if (v & 0xFFFFu) atomicAdd(&rep[2 * i],     v & 0xFFFFu);
        if (v >> 16)     atomicAdd(&rep[2 * i + 1], v >> 16);
    }
}

// ---------------------------------------------------------------------------
// Scan pass 0: sum NREP replicas of 8192 bins, find cut digit for k=TOP_K.
// Writes state[1]=d0cut, state[0]=k_rem.
// ---------------------------------------------------------------------------
__global__ void __launch_bounds__(1024) k_scan0(const u32* __restrict__ hist0,
                                                u32* __restrict__ state) {
    __shared__ u32 wtot[16];
    int t = threadIdx.x, lane = t & 63, wv = t >> 6;
    int base = t * 8;
    u32 cnt[8];
    u32 s = 0;
    #pragma unroll
    for (int b = 0; b < 8; b++) {
        u32 c = 0;
        for (int r = 0; r < NREP; r++) c += hist0[(size_t)r * D0_BINS + base + b];
        cnt[b] = c; s += c;
    }
    u32 x = s;  // suffix-inclusive across lanes (higher lane = higher bins)
    for (int off = 1; off < 64; off <<= 1) {
        u32 v = (u32)__shfl_down((int)x, off, 64);
        if (lane + off < 64) x += v;
    }
    if (lane == 0) wtot[wv] = x;
    __syncthreads();
    u32 above = x - s;
    for (int w = wv + 1; w < 16; w++) above += wtot[w];
    u32 k = TOP_K;
    if (above < k && above + s >= k) {
        u32 cum = above;
        for (int b = 7; b >= 0; b--) {
            cum += cnt[b];
            if (cum >= k) { state[1] = (u32)(base + b); state[0] = k - (cum - cnt[b]); break; }
        }
    }
}

// Pass 1 histogram: anchors in the d0 cut bin, 16-bit digit = score bits [18:3].
// ~180K anchors over 64K bins => ~3/bin, no contention.
__global__ void k_hist1(const float* __restrict__ scores, int A,
                        u32* __restrict__ hist1, const u32* __restrict__ state) {
    int a = blockIdx.x * blockDim.x + threadIdx.x;
    if (a >= A) return;
    u32 key = order_f32(scores[a]);
    if ((key >> (32 - D0_BITS)) == state[1]) atomicAdd(&hist1[(key >> 3) & 0xFFFFu], 1u);
}

// Scan pass 1: 64K flat bins, k=state[0]. Writes state[2]=d1cut.
__global__ void __launch_bounds__(1024) k_scan1(const u32* __restrict__ hist,
                                                u32* __restrict__ state) {
    __shared__ u32 wtot[16];
    int t = threadIdx.x, lane = t & 63, wv = t >> 6;
    u32 k = state[0];
    int base = t * 64;
    u32 s = 0;
    for (int i = 0; i < 64; i++) s += hist[base + i];
    u32 x = s;
    for (int off = 1; off < 64; off <<= 1) {
        u32 v = (u32)__shfl_down((int)x, off, 64);
        if (lane + off < 64) x += v;
    }
    if (lane == 0) wtot[wv] = x;
    __syncthreads();
    u32 above = x - s;
    for (int w = wv + 1; w < 16; w++) above += wtot[w];
    if (above < k && above + s >= k) {
        u32 cum = above;
        for (int b = 63; b >= 0; b--) {
            u32 c = hist[base + b];
            cum += c;
            if (cum >= k) { state[2] = (u32)(base + b); break; }
        }
    }
}

// Compact: every anchor whose 29-bit score prefix (bits 31:3) >= cut prefix.
// Count = (#above cut) + (#in cut bin) in [1000, ~1030] -- cap 2048.
__global__ void k_compact(const float* __restrict__ scores, int A,
                          u32* __restrict__ state, u32* __restrict__ cand) {
    int a = blockIdx.x * blockDim.x + threadIdx.x;
    if (a >= A) return;
    u32 key = order_f32(scores[a]);
    u32 pfx = key >> 3;
    u32 cut = (state[1] << 16) | state[2];
    if (pfx >= cut) {
        u32 p = atomicAdd(&state[5], 1u);
        if (p < CAND_CAP) cand[p] = a;
    }
}

// Bitonic sort 2048 u64 keys descending (exact lax.top_k order incl. index
// tie-break), take first TOP_K, decode+clip boxes.
__global__ void __launch_bounds__(1024)
k_sort_decode(const float* __restrict__ scores, const u32* __restrict__ cand,
              const u32* __restrict__ state,
              const float* __restrict__ anchors, const float* __restrict__ regs,
              const int* __restrict__ pH, const int* __restrict__ pW,
              u32* __restrict__ sidx, float* __restrict__ sscore,
              float* __restrict__ cbox) {
    __shared__ u64 keys[CAND_CAP];
    int t = threadIdx.x;
    int n = (int)state[5]; if (n > CAND_CAP) n = CAND_CAP;
    for (int i = t; i < CAND_CAP; i += 1024) {
        u64 kk = 0ull;  // real keys always > 0; pads sort last
        if (i < n) {
            u32 a = cand[i];
            kk = ((u64)order_f32(scores[a]) << 32) | (0xFFFFFFFFu - a);
        }
        keys[i] = kk;
    }
    __syncthreads();
    for (int k = 2; k <= CAND_CAP; k <<= 1) {
        for (int j = k >> 1; j > 0; j >>= 1) {
            for (int idx = t; idx < CAND_CAP; idx += 1024) {
                int ixj = idx ^ j;
                if (ixj > idx) {
                    u64 va = keys[idx], vb = keys[ixj];
                    bool desc = ((idx & k) == 0);
                    if (desc ? (va < vb) : (va > vb)) { keys[idx] = vb; keys[ixj] = va; }
                }
            }
            __syncthreads();
        }
    }
    if (t < TOP_K) {
        u64 key = keys[t];
        u32 a = 0xFFFFFFFFu - (u32)(key & 0xFFFFFFFFull);
        sidx[t] = a;
        u32 kk = (u32)(key >> 32);
        u32 bits = (kk & 0x80000000u) ? (kk & 0x7FFFFFFFu) : ~kk;
        sscore[t] = __uint_as_float(bits);
        float4 an = *(const float4*)(anchors + (size_t)a * 4);
        float4 rg = *(const float4*)(regs + (size_t)a * 4);
        float aw = an.z - an.x, ah = an.w - an.y;
        float acx = an.x + 0.5f * aw, acy = an.y + 0.5f * ah;
        float pcx = acx + (rg.x * 0.1f) * aw;
        float pcy = acy + (rg.y * 0.1f) * ah;
        float pw = expf(rg.z * 0.2f) * aw;
        float ph = expf(rg.w * 0.2f) * ah;
        float W = (float)(*pW), H = (float)(*pH);
        cbox[t * 4 + 0] = fminf(fmaxf(pcx - 0.5f * pw, 0.0f), W);
        cbox[t * 4 + 1] = fminf(fmaxf(pcy - 0.5f * ph, 0.0f), H);
        cbox[t * 4 + 2] = fminf(fmaxf(pcx + 0.5f * pw, 0.0f), W);
        cbox[t * 4 + 3] = fminf(fmaxf(pcy + 0.5f * ph, 0.0f), H);
    }
}

// Suppression bit-matrix: M[i][w] bit b = (j = w*64+b) suppressed by i (j>i).
__global__ void k_iou(const float* __restrict__ cbox, u64* __restrict__ M) {
    __shared__ float4 boxes[TOP_K];
    int t = threadIdx.x;
    for (int j = t; j < TOP_K; j += 256) boxes[j] = ((const float4*)cbox)[j];
    __syncthreads();
    int wv = t >> 6, lane = t & 63;
    int i = blockIdx.x * 4 + wv;
    if (i < TOP_K) {
        float4 bi = boxes[i];
        float ai = fmaxf(bi.z - bi.x, 0.0f) * fmaxf(bi.w - bi.y, 0.0f);
        for (int w = 0; w < 16; w++) {
            int j = w * 64 + lane;
            bool sup = false;
            if (j < TOP_K && j > i) {
                float4 bj = boxes[j];
                float aj = fmaxf(bj.z - bj.x, 0.0f) * fmaxf(bj.w - bj.y, 0.0f);
                float xx1 = fmaxf(bi.x, bj.x), yy1 = fmaxf(bi.y, bj.y);
                float xx2 = fminf(bi.z, bj.z), yy2 = fminf(bi.w, bj.w);
                float inter = fmaxf(xx2 - xx1, 0.0f) * fmaxf(yy2 - yy1, 0.0f);
                float iou = inter / (ai + aj - inter + 1e-8f);
                sup = iou > IOU_THRESH;
            }
            u64 mask = __ballot(sup ? 1 : 0);
            if (lane == 0) M[(size_t)i * 16 + w] = mask;
        }
    }
}

// Fused: sequential greedy NMS over LDS-staged M chunks + final gather/output.
__global__ void __launch_bounds__(256)
k_nms_fin(const float* __restrict__ sscore, const u64* __restrict__ M,
          const u32* __restrict__ sidx, const float* __restrict__ cbox,
          const float* __restrict__ cls, int C, float* __restrict__ out) {
    __shared__ u64 Ml[256 * 16];   // 32KB chunk of M
    __shared__ u64 keepS[16];
    __shared__ int det[MAX_DET];
    int t = threadIdx.x;
    if (t < 16) {
        u64 kk = 0ull;
        for (int b = 0; b < 64; b++) {
            int j = t * 64 + b;
            if (j < TOP_K && sscore[j] > SCORE_THRESH) kk |= (1ull << b);
        }
        keepS[t] = kk;
    }
    __syncthreads();
    for (int chunk = 0; chunk < 4; chunk++) {
        int row0 = chunk * 256;
        int nrows = (TOP_K - row0 < 256) ? (TOP_K - row0) : 256;
        for (int i = t; i < nrows * 16; i += 256) Ml[i] = M[(size_t)row0 * 16 + i];
        __syncthreads();
        if (t < 64) {   // wave 0 does the (inherently serial) greedy pass
            u64 kp = (t < 16) ? keepS[t] : 0ull;
            for (int r = 0; r < nrows; r++) {
                int i = row0 + r;
                u64 kw = __shfl(kp, i >> 6, 64);
                if ((kw >> (i & 63)) & 1ull) {
                    u64 m = (t < 16) ? Ml[r * 16 + t] : 0ull;
                    kp &= ~m;
                }
            }
            if (t < 16) keepS[t] = kp;
        }
        __syncthreads();
    }
    if (t == 0) {
        int cnt = 0;
        for (int w = 0; w < 16 && cnt < MAX_DET; w++) {
            u64 kw = keepS[w];
            while (kw && cnt < MAX_DET) {
                int b = __ffsll(kw) - 1;
                det[cnt++] = w * 64 + b;
                kw &= kw - 1;
            }
        }
        for (; cnt < MAX_DET; cnt++) det[cnt] = -1;
    }
    __syncthreads();
    if (t < MAX_DET) {
        int i = det[t];
        if (i >= 0) {
            u32 a = sidx[i];
            const float* p = cls + (size_t)a * C;
            float best = -1e30f; int bc = 0;
            if (C == 80) {
                #pragma unroll
                for (int c4 = 0; c4 < 20; c4++) {
                    float4 v = *(const float4*)(p + c4 * 4);
                    if (v.x > best) { best = v.x; bc = c4 * 4; }
                    if (v.y > best) { best = v.y; bc = c4 * 4 + 1; }
                    if (v.z > best) { best = v.z; bc = c4 * 4 + 2; }
                    if (v.w > best) { best = v.w; bc = c4 * 4 + 3; }
                }
            } else {
                best = p[0]; bc = 0;
                for (int c = 1; c < C; c++) { float v = p[c]; if (v > best) { best = v; bc = c; } }
            }
            out[t] = best;
            out[MAX_DET + t] = (float)bc;
            out[2 * MAX_DET + t * 4 + 0] = cbox[i * 4 + 0];
            out[2 * MAX_DET + t * 4 + 1] = cbox[i * 4 + 1];
            out[2 * MAX_DET + t * 4 + 2] = cbox[i * 4 + 2];
            out[2 * MAX_DET + t * 4 + 3] = cbox[i * 4 + 3];
        } else {
            out[t] = 0.0f;
            out[MAX_DET + t] = -1.0f;
            out[2 * MAX_DET + t * 4 + 0] = 0.0f;
            out[2 * MAX_DET + t * 4 + 1] = 0.0f;
            out[2 * MAX_DET + t * 4 + 2] = 0.0f;
            out[2 * MAX_DET + t * 4 + 3] = 0.0f;
        }
    }
}

extern "C" void kernel_launch(void* const* d_in, const int* in_sizes, int n_in,
                              void* d_out, int out_size, void* d_ws, size_t ws_size,
                              hipStream_t stream) {
    const float* cls     = (const float*)d_in[0];
    const float* regs    = (const float*)d_in[1];
    const float* anchors = (const float*)d_in[2];
    const int*   pH      = (const int*)d_in[3];
    const int*   pW      = (const int*)d_in[4];
    int A = in_sizes[1] / 4;
    int C = in_sizes[0] / A;

    char* ws = (char*)d_ws;
    u32*   hist0  = (u32*)(ws + OFF_HIST0);
    u32*   hist1  = (u32*)(ws + OFF_HIST1);
    u32*   state  = (u32*)(ws + OFF_STATE);
    u32*   cand   = (u32*)(ws + OFF_CAND);
    u32*   sidx   = (u32*)(ws + OFF_SIDX);
    float* sscore = (float*)(ws + OFF_SSCORE);
    float* cbox   = (float*)(ws + OFF_CBOX);
    u64*   M      = (u64*)(ws + OFF_M);
    float* scores = (float*)(ws + OFF_SCORES);

    // zero hist0 + hist1 + state in one memset (~786KB)
    hipMemsetAsync(ws, 0, OFF_STATE + 32, stream);

    if (C == 80) {
        int nb1 = (A + 383) / 384;
        k1_scores<<<nb1, 256, 0, stream>>>(cls, A, scores, hist0);
    } else {
        int nb1 = (A + 511) / 512;
        k1_generic<<<nb1, 256, 0, stream>>>(cls, A, C, scores, hist0);
    }
    k_scan0<<<1, 1024, 0, stream>>>(hist0, state);
    int nb = (A + 255) / 256;
    k_hist1<<<nb, 256, 0, stream>>>(scores, A, hist1, state);
    k_scan1<<<1, 1024, 0, stream>>>(hist1, state);
    k_compact<<<nb, 256, 0, stream>>>(scores, A, state, cand);
    k_sort_decode<<<1, 1024, 0, stream>>>(scores, cand, state, anchors, regs, pH, pW,
                                          sidx, sscore, cbox);
    k_iou<<<(TOP_K + 3) / 4, 256, 0, stream>>>(cbox, M);
    k_nms_fin<<<1, 256, 0, stream>>>(sscore, M, sidx, cbox, cls, C, (float*)d_out);
}

// Round 3
// 192.186 us; speedup vs baseline: 4.6795x; 1.6250x over previous
//
#include <hip/hip_runtime.h>
#include <stdint.h>

#define SCORE_THRESH 0.05f
#define IOU_THRESH 0.5f
#define TOP_K 1000
#define MAX_DET 100

#define D0_BITS 13
#define D0_BINS 8192           // 2^13
#define NREP 16                // replicated pass-0 histograms
#define CAND_CAP 2048

typedef unsigned int u32;
typedef unsigned long long u64;

// ---- ws layout (bytes) ----
#define OFF_HIST0    0          // u32[NREP*8192] = 524288
#define OFF_HIST1    524288     // u32[65536]     = 262144 -> 786432
#define OFF_STATE    786432     // u32[8]: [0]=k_rem [1]=d0cut [2]=d1cut [5]=cand_cnt
#define OFF_CAND     786464     // u32[2048]  -> 794656   (rowflag aliases this later)
#define OFF_SIDX     794656     // u32[1000]  -> 798656
#define OFF_SSCORE   798656     // float[1000]-> 802656
#define OFF_CBOX     802656     // float[4000]-> 818656 (16B aligned)
#define OFF_M        818656     // u64[1000*16] = 128000 -> 946656
#define OFF_SCORES   946656     // float[A]

__device__ __forceinline__ u32 order_f32(float f) {
    u32 b = __float_as_uint(f);
    return (b & 0x80000000u) ? ~b : (b | 0x80000000u);
}

// ---------------------------------------------------------------------------
// K1: coalesced class-max (4 lanes per anchor, float4), thresholded score,
// LDS-privatized 13-bit pass-0 histogram, flushed to replicated global hist.
// ---------------------------------------------------------------------------
__global__ void __launch_bounds__(256) k1_scores(const float* __restrict__ cls, int A,
                                                 float* __restrict__ scores,
                                                 u32* __restrict__ hist0) {
    __shared__ u32 hl[D0_BINS / 2];   // u16-packed counts (per-block max 384 < 65536)
    int t = threadIdx.x;
    for (int i = t; i < D0_BINS / 2; i += 256) hl[i] = 0;
    __syncthreads();

    int sub = t & 3;          // which 20-float chunk of the anchor's 80 classes
    int la  = t >> 2;         // local anchor 0..63
    for (int s = 0; s < 6; s++) {
        int a = (blockIdx.x * 6 + s) * 64 + la;
        float m = -1e30f;
        if (a < A) {
            const float* p = cls + (size_t)a * 80 + sub * 4;
            #pragma unroll
            for (int k2 = 0; k2 < 5; k2++) {
                float4 v = *(const float4*)(p + k2 * 16);
                m = fmaxf(m, fmaxf(fmaxf(v.x, v.y), fmaxf(v.z, v.w)));
            }
        }
        m = fmaxf(m, __shfl_xor(m, 1, 64));
        m = fmaxf(m, __shfl_xor(m, 2, 64));
        if (sub == 0 && a < A) {
            float s0 = (m > SCORE_THRESH) ? m : -1.0f;
            scores[a] = s0;
            u32 d = order_f32(s0) >> (32 - D0_BITS);
            atomicAdd(&hl[d >> 1], (d & 1) ? 0x10000u : 1u);
        }
    }
    __syncthreads();
    u32* rep = hist0 + (size_t)(blockIdx.x & (NREP - 1)) * D0_BINS;
    for (int i = t; i < D0_BINS / 2; i += 256) {
        u32 v = hl[i];
        if (v & 0xFFFFu) atomicAdd(&rep[2 * i],     v & 0xFFFFu);
        if (v >> 16)     atomicAdd(&rep[2 * i + 1], v >> 16);
    }
}

// Generic-C fallback (correctness insurance if C != 80).
__global__ void __launch_bounds__(256) k1_generic(const float* __restrict__ cls, int A, int C,
                                                  float* __restrict__ scores,
                                                  u32* __restrict__ hist0) {
    __shared__ u32 hl[D0_BINS / 2];
    int t = threadIdx.x;
    for (int i = t; i < D0_BINS / 2; i += 256) hl[i] = 0;
    __syncthreads();
    for (int s = 0; s < 2; s++) {
        int a = blockIdx.x * 512 + s * 256 + t;
        if (a < A) {
            const float* p = cls + (size_t)a * C;
            float m = -1e30f;
            for (int c = 0; c < C; c++) m = fmaxf(m, p[c]);
            float s0 = (m > SCORE_THRESH) ? m : -1.0f;
            scores[a] = s0;
            u32 d = order_f32(s0) >> (32 - D0_BITS);
            atomicAdd(&hl[d >> 1], (d & 1) ? 0x10000u : 1u);
        }
    }
    __syncthreads();
    u32* rep = hist0 + (size_t)(blockIdx.x & (NREP - 1)) * D0_BINS;
    for (int i = t; i < D0_BINS / 2; i += 256) {
        u32 v = hl[i];
        if (v & 0xFFFFu) atomicAdd(&rep[2 * i],     v & 0xFFFFu);
        if (v >> 16)     atomicAdd(&rep[2 * i + 1], v >> 16);
    }
}

// Scan pass 0: sum NREP replicas of 8192 bins, find cut digit for k=TOP_K.
__global__ void __launch_bounds__(1024) k_scan0(const u32* __restrict__ hist0,
                                                u32* __restrict__ state) {
    __shared__ u32 wtot[16];
    int t = threadIdx.x, lane = t & 63, wv = t >> 6;
    int base = t * 8;
    u32 cnt[8];
    u32 s = 0;
    #pragma unroll
    for (int b = 0; b < 8; b++) {
        u32 c = 0;
        for (int r = 0; r < NREP; r++) c += hist0[(size_t)r * D0_BINS + base + b];
        cnt[b] = c; s += c;
    }
    u32 x = s;  // suffix-inclusive across lanes (higher lane = higher bins)
    for (int off = 1; off < 64; off <<= 1) {
        u32 v = (u32)__shfl_down((int)x, off, 64);
        if (lane + off < 64) x += v;
    }
    if (lane == 0) wtot[wv] = x;
    __syncthreads();
    u32 above = x - s;
    for (int w = wv + 1; w < 16; w++) above += wtot[w];
    u32 k = TOP_K;
    if (above < k && above + s >= k) {
        u32 cum = above;
        for (int b = 7; b >= 0; b--) {
            cum += cnt[b];
            if (cum >= k) { state[1] = (u32)(base + b); state[0] = k - (cum - cnt[b]); break; }
        }
    }
}

// Pass 1 histogram: anchors in the d0 cut bin, digit = key bits [18:3].
__global__ void k_hist1(const float* __restrict__ scores, int A,
                        u32* __restrict__ hist1, const u32* __restrict__ state) {
    int a = blockIdx.x * blockDim.x + threadIdx.x;
    if (a >= A) return;
    u32 key = order_f32(scores[a]);
    if ((key >> (32 - D0_BITS)) == state[1]) atomicAdd(&hist1[(key >> 3) & 0xFFFFu], 1u);
}

// Scan pass 1: 64K flat bins, k=state[0]. Writes state[2]=d1cut.
__global__ void __launch_bounds__(1024) k_scan1(const u32* __restrict__ hist,
                                                u32* __restrict__ state) {
    __shared__ u32 wtot[16];
    int t = threadIdx.x, lane = t & 63, wv = t >> 6;
    u32 k = state[0];
    int base = t * 64;
    u32 s = 0;
    for (int i = 0; i < 64; i++) s += hist[base + i];
    u32 x = s;
    for (int off = 1; off < 64; off <<= 1) {
        u32 v = (u32)__shfl_down((int)x, off, 64);
        if (lane + off < 64) x += v;
    }
    if (lane == 0) wtot[wv] = x;
    __syncthreads();
    u32 above = x - s;
    for (int w = wv + 1; w < 16; w++) above += wtot[w];
    if (above < k && above + s >= k) {
        u32 cum = above;
        for (int b = 63; b >= 0; b--) {
            u32 c = hist[base + b];
            cum += c;
            if (cum >= k) { state[2] = (u32)(base + b); break; }
        }
    }
}

// Compact: every anchor whose 29-bit score prefix >= cut prefix (n in [1000,~1030]).
__global__ void k_compact(const float* __restrict__ scores, int A,
                          u32* __restrict__ state, u32* __restrict__ cand) {
    int a = blockIdx.x * blockDim.x + threadIdx.x;
    if (a >= A) return;
    u32 key = order_f32(scores[a]);
    u32 pfx = key >> 3;
    u32 cut = (state[1] << 16) | state[2];
    if (pfx >= cut) {
        u32 p = atomicAdd(&state[5], 1u);
        if (p < CAND_CAP) cand[p] = a;
    }
}

// Bitonic sort N (1024 or 2048) u64 keys descending (exact lax.top_k order incl.
// index tie-break), take first TOP_K, decode+clip boxes.
__global__ void __launch_bounds__(1024)
k_sort_decode(const float* __restrict__ scores, const u32* __restrict__ cand,
              const u32* __restrict__ state,
              const float* __restrict__ anchors, const float* __restrict__ regs,
              const int* __restrict__ pH, const int* __restrict__ pW,
              u32* __restrict__ sidx, float* __restrict__ sscore,
              float* __restrict__ cbox) {
    __shared__ u64 keys[CAND_CAP];
    int t = threadIdx.x;
    int n = (int)state[5]; if (n > CAND_CAP) n = CAND_CAP;
    int N = (n <= 1024) ? 1024 : CAND_CAP;
    for (int i = t; i < N; i += 1024) {
        u64 kk = 0ull;  // real keys always > 0; pads sort last
        if (i < n) {
            u32 a = cand[i];
            kk = ((u64)order_f32(scores[a]) << 32) | (0xFFFFFFFFu - a);
        }
        keys[i] = kk;
    }
    __syncthreads();
    for (int k = 2; k <= N; k <<= 1) {
        for (int j = k >> 1; j > 0; j >>= 1) {
            for (int idx = t; idx < N; idx += 1024) {
                int ixj = idx ^ j;
                if (ixj > idx) {
                    u64 va = keys[idx], vb = keys[ixj];
                    bool desc = ((idx & k) == 0);
                    if (desc ? (va < vb) : (va > vb)) { keys[idx] = vb; keys[ixj] = va; }
                }
            }
            __syncthreads();
        }
    }
    if (t < TOP_K) {
        u64 key = keys[t];
        u32 a = 0xFFFFFFFFu - (u32)(key & 0xFFFFFFFFull);
        sidx[t] = a;
        u32 kk = (u32)(key >> 32);
        u32 bits = (kk & 0x80000000u) ? (kk & 0x7FFFFFFFu) : ~kk;
        sscore[t] = __uint_as_float(bits);
        float4 an = *(const float4*)(anchors + (size_t)a * 4);
        float4 rg = *(const float4*)(regs + (size_t)a * 4);
        float aw = an.z - an.x, ah = an.w - an.y;
        float acx = an.x + 0.5f * aw, acy = an.y + 0.5f * ah;
        float pcx = acx + (rg.x * 0.1f) * aw;
        float pcy = acy + (rg.y * 0.1f) * ah;
        float pw = expf(rg.z * 0.2f) * aw;
        float ph = expf(rg.w * 0.2f) * ah;
        float W = (float)(*pW), H = (float)(*pH);
        cbox[t * 4 + 0] = fminf(fmaxf(pcx - 0.5f * pw, 0.0f), W);
        cbox[t * 4 + 1] = fminf(fmaxf(pcy - 0.5f * ph, 0.0f), H);
        cbox[t * 4 + 2] = fminf(fmaxf(pcx + 0.5f * pw, 0.0f), W);
        cbox[t * 4 + 3] = fminf(fmaxf(pcy + 0.5f * ph, 0.0f), H);
    }
}

// Suppression bit-matrix + per-row "has any suppression" flag.
__global__ void k_iou(const float* __restrict__ cbox, u64* __restrict__ M,
                      u32* __restrict__ rflag) {
    __shared__ float4 boxes[TOP_K];
    int t = threadIdx.x;
    for (int j = t; j < TOP_K; j += 256) boxes[j] = ((const float4*)cbox)[j];
    __syncthreads();
    int wv = t >> 6, lane = t & 63;
    int i = blockIdx.x * 4 + wv;
    if (i < TOP_K) {
        float4 bi = boxes[i];
        float ai = fmaxf(bi.z - bi.x, 0.0f) * fmaxf(bi.w - bi.y, 0.0f);
        u64 any = 0ull;
        for (int w = 0; w < 16; w++) {
            int j = w * 64 + lane;
            bool sup = false;
            if (j < TOP_K && j > i) {
                float4 bj = boxes[j];
                float aj = fmaxf(bj.z - bj.x, 0.0f) * fmaxf(bj.w - bj.y, 0.0f);
                float xx1 = fmaxf(bi.x, bj.x), yy1 = fmaxf(bi.y, bj.y);
                float xx2 = fminf(bi.z, bj.z), yy2 = fminf(bi.w, bj.w);
                float inter = fmaxf(xx2 - xx1, 0.0f) * fmaxf(yy2 - yy1, 0.0f);
                float iou = inter / (ai + aj - inter + 1e-8f);
                sup = iou > IOU_THRESH;
            }
            u64 mask = __ballot(sup ? 1 : 0);
            if (lane == 0) { M[(size_t)i * 16 + w] = mask; any |= mask; }
        }
        if (lane == 0) rflag[i] = (any != 0ull) ? 1u : 0u;
    }
}

// Fused NMS + finalize. Greedy chain compressed to rows with non-zero masks:
// zero-mask rows can never change the keep state, so skipping them preserves
// the exact sequential-greedy semantics.
__global__ void __launch_bounds__(256)
k_nms_fin(const float* __restrict__ sscore, const u64* __restrict__ M,
          const u32* __restrict__ rflag,
          const u32* __restrict__ sidx, const float* __restrict__ cbox,
          const float* __restrict__ cls, int C, float* __restrict__ out) {
    __shared__ u32 nib[256];
    __shared__ u64 keepS[16];
    __shared__ int act[TOP_K];
    __shared__ u32 wsum[4];
    __shared__ int nactS;
    __shared__ u64 Ml[256 * 16];   // 32 KB chunk of active-row masks
    __shared__ int det[MAX_DET];
    int t = threadIdx.x;
    int lane = t & 63, wv = t >> 6;

    // --- keep init: thread t covers j = 4t..4t+3 ---
    {
        u32 nb = 0;
        int j0 = 4 * t;
        #pragma unroll
        for (int q = 0; q < 4; q++) {
            int j = j0 + q;
            if (j < TOP_K && sscore[j] > SCORE_THRESH) nb |= (1u << q);
        }
        nib[t] = nb;
    }
    // --- ordered active-row list via block prefix scan ---
    u32 flags = 0; int cnt = 0;
    {
        int r0 = 4 * t;
        #pragma unroll
        for (int q = 0; q < 4; q++) {
            int r = r0 + q;
            if (r < TOP_K && rflag[r]) { flags |= (1u << q); cnt++; }
        }
    }
    int x = cnt;
    for (int off = 1; off < 64; off <<= 1) {
        int v = __shfl_up(x, off, 64);
        if (lane >= off) x += v;
    }
    if (lane == 63) wsum[wv] = (u32)x;
    __syncthreads();
    if (t < 16) {
        u64 w = 0;
        for (int m = 0; m < 16; m++) w |= ((u64)nib[t * 16 + m]) << (4 * m);
        keepS[t] = w;
    }
    int base = 0;
    for (int w = 0; w < wv; w++) base += (int)wsum[w];
    int pos = base + x - cnt;
    {
        int r0 = 4 * t;
        #pragma unroll
        for (int q = 0; q < 4; q++)
            if (flags & (1u << q)) act[pos++] = r0 + q;
    }
    if (t == 0) { int na = 0; for (int w = 0; w < 4; w++) na += (int)wsum[w]; nactS = na; }
    __syncthreads();
    int nact = nactS;

    // --- chunked greedy over active rows only ---
    for (int c0 = 0; c0 < nact; c0 += 256) {
        int cn = (nact - c0 < 256) ? (nact - c0) : 256;
        for (int i = t; i < cn * 16; i += 256) {
            int row = act[c0 + (i >> 4)];
            Ml[i] = M[(size_t)row * 16 + (i & 15)];
        }
        __syncthreads();
        if (wv == 0) {
            u64 kp = (lane < 16) ? keepS[lane] : 0ull;
            for (int k = 0; k < cn; k++) {
                int i = act[c0 + k];
                u64 kw = __shfl(kp, i >> 6, 64);
                if ((kw >> (i & 63)) & 1ull) {
                    u64 m = (lane < 16) ? Ml[k * 16 + lane] : 0ull;
                    kp &= ~m;
                }
            }
            if (lane < 16) keepS[lane] = kp;
        }
        __syncthreads();
    }

    // --- first MAX_DET kept (ascending = score-desc order) ---
    if (t == 0) {
        int cnt2 = 0;
        for (int w = 0; w < 16 && cnt2 < MAX_DET; w++) {
            u64 kw = keepS[w];
            while (kw && cnt2 < MAX_DET) {
                int b = __ffsll(kw) - 1;
                det[cnt2++] = w * 64 + b;
                kw &= kw - 1;
            }
        }
        for (; cnt2 < MAX_DET; cnt2++) det[cnt2] = -1;
    }
    __syncthreads();
    if (t < MAX_DET) {
        int i = det[t];
        if (i >= 0) {
            u32 a = sidx[i];
            const float* p = cls + (size_t)a * C;
            float best = -1e30f; int bc = 0;
            if (C == 80) {
                #pragma unroll
                for (int c4 = 0; c4 < 20; c4++) {
                    float4 v = *(const float4*)(p + c4 * 4);
                    if (v.x > best) { best = v.x; bc = c4 * 4; }
                    if (v.y > best) { best = v.y; bc = c4 * 4 + 1; }
                    if (v.z > best) { best = v.z; bc = c4 * 4 + 2; }
                    if (v.w > best) { best = v.w; bc = c4 * 4 + 3; }
                }
            } else {
                best = p[0]; bc = 0;
                for (int c = 1; c < C; c++) { float v = p[c]; if (v > best) { best = v; bc = c; } }
            }
            out[t] = best;
            out[MAX_DET + t] = (float)bc;
            out[2 * MAX_DET + t * 4 + 0] = cbox[i * 4 + 0];
            out[2 * MAX_DET + t * 4 + 1] = cbox[i * 4 + 1];
            out[2 * MAX_DET + t * 4 + 2] = cbox[i * 4 + 2];
            out[2 * MAX_DET + t * 4 + 3] = cbox[i * 4 + 3];
        } else {
            out[t] = 0.0f;
            out[MAX_DET + t] = -1.0f;
            out[2 * MAX_DET + t * 4 + 0] = 0.0f;
            out[2 * MAX_DET + t * 4 + 1] = 0.0f;
            out[2 * MAX_DET + t * 4 + 2] = 0.0f;
            out[2 * MAX_DET + t * 4 + 3] = 0.0f;
        }
    }
}

extern "C" void kernel_launch(void* const* d_in, const int* in_sizes, int n_in,
                              void* d_out, int out_size, void* d_ws, size_t ws_size,
                              hipStream_t stream) {
    const float* cls     = (const float*)d_in[0];
    const float* regs    = (const float*)d_in[1];
    const float* anchors = (const float*)d_in[2];
    const int*   pH      = (const int*)d_in[3];
    const int*   pW      = (const int*)d_in[4];
    int A = in_sizes[1] / 4;
    int C = in_sizes[0] / A;

    char* ws = (char*)d_ws;
    u32*   hist0  = (u32*)(ws + OFF_HIST0);
    u32*   hist1  = (u32*)(ws + OFF_HIST1);
    u32*   state  = (u32*)(ws + OFF_STATE);
    u32*   cand   = (u32*)(ws + OFF_CAND);
    u32*   rflag  = (u32*)(ws + OFF_CAND);   // aliases cand (dead after sort)
    u32*   sidx   = (u32*)(ws + OFF_SIDX);
    float* sscore = (float*)(ws + OFF_SSCORE);
    float* cbox   = (float*)(ws + OFF_CBOX);
    u64*   M      = (u64*)(ws + OFF_M);
    float* scores = (float*)(ws + OFF_SCORES);

    // zero hist0 + hist1 + state in one memset (~786KB)
    hipMemsetAsync(ws, 0, OFF_STATE + 32, stream);

    if (C == 80) {
        int nb1 = (A + 383) / 384;
        k1_scores<<<nb1, 256, 0, stream>>>(cls, A, scores, hist0);
    } else {
        int nb1 = (A + 511) / 512;
        k1_generic<<<nb1, 256, 0, stream>>>(cls, A, C, scores, hist0);
    }
    k_scan0<<<1, 1024, 0, stream>>>(hist0, state);
    int nb = (A + 255) / 256;
    k_hist1<<<nb, 256, 0, stream>>>(scores, A, hist1, state);
    k_scan1<<<1, 1024, 0, stream>>>(hist1, state);
    k_compact<<<nb, 256, 0, stream>>>(scores, A, state, cand);
    k_sort_decode<<<1, 1024, 0, stream>>>(scores, cand, state, anchors, regs, pH, pW,
                                          sidx, sscore, cbox);
    k_iou<<<(TOP_K + 3) / 4, 256, 0, stream>>>(cbox, M, rflag);
    k_nms_fin<<<1, 256, 0, stream>>>(sscore, M, rflag, sidx, cbox, cls, C, (float*)d_out);
}